// Round 1
// baseline (125.767 us; speedup 1.0000x reference)
//
#include <hip/hip_runtime.h>

#define EPSF 1e-12f
#define STILE 64
#define KK 64
#define RSTR 65                 // row stride in float4 units (1040 B -> start slot (col+idx)%8)
#define FSTR (4 * RSTR)         // 260 floats per coefficient row
#define BLK 1024
#define NWAVE (BLK / 64)        // 16 waves
#define PRELOOP ((STILE * KK) / BLK)  // 4
#define UNROLL 4                // 2-row batches per unrolled iter

__device__ __forceinline__ float sgnf(float x) {
    return (x > 0.f) ? 1.f : ((x < 0.f) ? -1.f : 0.f);
}

// One ds_read_b128 per element: cf[row] holds {c0,c1,c2,c3} per interval.
__device__ __forceinline__ float eval1(float x, const float4* __restrict__ q,
                                       float af, float bf) {
    float tf = fmaf(x, af, bf);
    float tcf = fminf(fmaxf(tf, 0.f), (float)(KK - 1));
    int idx = min((int)tcf, KK - 2);
    float t = tcf - (float)idx;
    float4 c = q[idx];
    float P = fmaf(fmaf(fmaf(c.w, t, c.z), t, c.y), t, c.x);
    float w = fmaf(fmaf(t, 2.f, t), c.w, c.z + c.z);  // 3t*c3 + 2c2
    float Pp = fmaf(t, w, c.y);                       // P'(t)
    return fmaf(Pp, tf - tcf, P);                     // branch-free extrapolation
}

__global__ __launch_bounds__(BLK, 8) void pchip_fused3(
    const float* __restrict__ xq,
    const float* __restrict__ coeffs,
    const float* __restrict__ knots,
    float* __restrict__ out,
    int S, int b_chunk)
{
    __shared__ float4 cf4[STILE * RSTR];   // 66560 B: interleaved c0..c3
    __shared__ float skn[KK];
    float* cf = (float*)cf4;

    int tid = threadIdx.x;
    int s0 = blockIdx.x * STILE;
    int b0 = blockIdx.y * b_chunk;

    if (tid < KK) skn[tid] = knots[tid];
    // stage y into slot 0 (coalesced global read)
#pragma unroll
    for (int i = 0; i < PRELOOP; i++) {
        int p = tid + i * BLK;
        int sl = p >> 6, k = p & 63;
        cf[sl * FSTR + 4 * k] = coeffs[(size_t)(s0 + sl) * KK + k];
    }
    __syncthreads();
    // delta[k] into slot 3 (reads slot 0 only -> no hazard within phase)
#pragma unroll
    for (int i = 0; i < PRELOOP; i++) {
        int p = tid + i * BLK;
        int sl = p >> 6, k = p & 63;
        if (k < KK - 1) {
            int ib = sl * FSTR + 4 * k;
            float hh = skn[k + 1] - skn[k];
            cf[ib + 3] = (cf[ib + 4] - cf[ib]) / (hh + EPSF);
        }
    }
    __syncthreads();
    // Fritsch-Carlson slopes d into slot 2 (reads slot 3 only -> disjoint, no roundtrip)
#pragma unroll
    for (int i = 0; i < PRELOOP; i++) {
        int p = tid + i * BLK;
        int sl = p >> 6, k = p & 63;
        int rb = sl * FSTR;
        float d;
        if (k == 0) {
            float h0 = skn[1] - skn[0], h1 = skn[2] - skn[1];
            float de0 = cf[rb + 3], de1 = cf[rb + 7];
            d = ((2.f * h0 + h1) * de0 - h0 * de1) / (h0 + h1 + EPSF);
            if (sgnf(d) != sgnf(de0)) d = 0.f;
            if ((sgnf(de0) != sgnf(de1)) && (fabsf(d) > 3.f * fabsf(de0))) d = 3.f * de0;
        } else if (k == KK - 1) {
            float hn1 = skn[KK - 1] - skn[KK - 2], hn2 = skn[KK - 2] - skn[KK - 3];
            float dn1 = cf[rb + 4 * (KK - 2) + 3], dn2 = cf[rb + 4 * (KK - 3) + 3];
            d = ((2.f * hn1 + hn2) * dn1 - hn1 * dn2) / (hn1 + hn2 + EPSF);
            if (sgnf(d) != sgnf(dn1)) d = 0.f;
            if ((sgnf(dn1) != sgnf(dn2)) && (fabsf(d) > 3.f * fabsf(dn1))) d = 3.f * dn1;
        } else {
            float dprev = cf[rb + 4 * (k - 1) + 3], dnext = cf[rb + 4 * k + 3];
            float hp = skn[k] - skn[k - 1], hn = skn[k + 1] - skn[k];
            bool same = dprev * dnext > 0.f;
            float w1 = 2.f * hn + hp;
            float w2 = hn + 2.f * hp;
            float denom = w1 / (dprev + EPSF) + w2 / (dnext + EPSF);
            float dint = (w1 + w2) / (denom + EPSF);
            d = same ? dint : 0.f;
        }
        cf[rb + 4 * k + 2] = d;
    }
    __syncthreads();
    // power-basis conversion: read y(k),y(k+1),d(k),d(k+1) -> regs, sync, write c1..c3
    float c1r[PRELOOP], c2r[PRELOOP], c3r[PRELOOP];
#pragma unroll
    for (int i = 0; i < PRELOOP; i++) {
        int p = tid + i * BLK;
        int sl = p >> 6, k = p & 63;
        int kc = min(k, KK - 2);
        int ib = sl * FSTR + 4 * kc;
        float y0 = cf[ib], y1 = cf[ib + 4];
        float d0 = cf[ib + 2], d1 = cf[ib + 6];
        float h = skn[kc + 1] - skn[kc] + EPSF;
        c1r[i] = h * d0;
        c2r[i] = 3.f * (y1 - y0) - h * (2.f * d0 + d1);
        c3r[i] = 2.f * (y0 - y1) + h * (d0 + d1);
    }
    __syncthreads();
#pragma unroll
    for (int i = 0; i < PRELOOP; i++) {
        int p = tid + i * BLK;
        int sl = p >> 6, k = p & 63;
        if (k < KK - 1) {
            int ib = sl * FSTR + 4 * k;
            cf[ib + 1] = c1r[i];
            cf[ib + 2] = c2r[i];
            cf[ib + 3] = c3r[i];
        }
    }
    __syncthreads();

    // ---- evaluation sweep: wave = 2 b-rows x 64 s-cols, float2 per lane ----
    float x0d = skn[0], x1d = skn[KK - 1];
    float invh = (float)(KK - 1) / (x1d - x0d);
    float af = invh, bf = -x0d * invh;
    int wave = tid >> 6, lane = tid & 63;
    int brow = lane >> 5;            // 0..1
    int scol = (lane & 31) << 1;     // 0,2,..,62
    const float4* q0 = cf4 + scol * RSTR;
    const float4* q1 = q0 + RSTR;

    int rows_per_wave = b_chunk / NWAVE;   // 32
    size_t off0 = (size_t)(b0 + wave * rows_per_wave + brow) * S + s0 + scol;
    int nb = rows_per_wave >> 1;           // 16 two-row batches
    for (int ii = 0; ii < nb; ii += UNROLL) {
        float2 xv[UNROLL];
#pragma unroll
        for (int j = 0; j < UNROLL; j++)
            xv[j] = *(const float2*)(xq + off0 + (size_t)(2 * j) * S);
#pragma unroll
        for (int j = 0; j < UNROLL; j++) {
            float2 r;
            r.x = eval1(xv[j].x, q0, af, bf);
            r.y = eval1(xv[j].y, q1, af, bf);
            *(float2*)(out + off0 + (size_t)(2 * j) * S) = r;
        }
        off0 += (size_t)(2 * UNROLL) * S;
    }
}

extern "C" void kernel_launch(void* const* d_in, const int* in_sizes, int n_in,
                              void* d_out, int out_size, void* d_ws, size_t ws_size,
                              hipStream_t stream) {
    const float* xq     = (const float*)d_in[0];
    const float* coeffs = (const float*)d_in[1];
    const float* knots  = (const float*)d_in[2];
    float* out = (float*)d_out;

    int K = in_sizes[2];           // 64
    int S = in_sizes[1] / K;       // 4096
    int N = in_sizes[0];           // B*S
    int B = N / S;                 // 4096

    int n_btiles = 8;              // 64 x 8 = 512 blocks -> exactly 2/CU at 1024 thr
    int b_chunk = B / n_btiles;    // 512 rows/block, 32 rows/wave
    dim3 grid(S / STILE, n_btiles);
    pchip_fused3<<<grid, BLK, 0, stream>>>(xq, coeffs, knots, out, S, b_chunk);
}